// Round 3
// baseline (64.510 us; speedup 1.0000x reference)
//
#include <hip/hip_runtime.h>
#include <hip/hip_bf16.h>

typedef __attribute__((ext_vector_type(8))) short bf16x8;
typedef __attribute__((ext_vector_type(4))) float f32x4;
typedef __attribute__((ext_vector_type(16))) float f32x16;
typedef __attribute__((ext_vector_type(2))) unsigned int u32x2;
typedef unsigned short u16;
typedef unsigned int u32;

#define EMB 128
#define HEADS 8
#define HD 16
#define NB 2
#define NN 128
#define SEQ (NB*NN)
#define NTOK (SEQ*NN)

// round-to-nearest-even fp32 -> bf16
static __device__ __forceinline__ u16 f2bf(float f) {
    union { float f; u32 u; } v; v.f = f;
    u32 u = v.u;
    return (u16)((u + 0x7FFFu + ((u >> 16) & 1u)) >> 16);
}

static __device__ __forceinline__ u32 cvtpk(float a, float b) {
    u32 r;
    asm("v_cvt_pk_bf16_f32 %0, %1, %2" : "=v"(r) : "v"(a), "v"(b));
    return r;
}

// exchange: a' = [a.lo32 | b.lo32(partner)], b' = [a.hi32(partner) | b.hi32]
static __device__ __forceinline__ void plswap(u32& a, u32& b) {
#if __has_builtin(__builtin_amdgcn_permlane32_swap)
    u32x2 r = __builtin_amdgcn_permlane32_swap(a, b, false, false);
    a = r[0]; b = r[1];
#else
    u32 sa = __shfl_xor(a, 32), sb = __shfl_xor(b, 32);
    bool hi = (threadIdx.x & 32) != 0;
    u32 na = hi ? sb : a;
    u32 nb = hi ? b : sa;
    a = na; b = nb;
#endif
}

// ---------------------------------------------------------------------------
// Weight prep: wt[mat][n][k] = bf16(w[mat][k][n]), mat: q,k,v,o
__global__ void __launch_bounds__(256) k_prep(const float* __restrict__ wq,
        const float* __restrict__ wk, const float* __restrict__ wv,
        const float* __restrict__ wo, u16* __restrict__ wt) {
    int i = blockIdx.x * 256 + threadIdx.x;
    int mat = i >> 14, rem = i & 16383;
    int k = rem >> 7, n = rem & 127;
    const float* src = mat == 0 ? wq : mat == 1 ? wk : mat == 2 ? wv : wo;
    wt[mat * 16384 + n * 128 + k] = f2bf(src[rem]);
}

// ---------------------------------------------------------------------------
// Fused LayerNorm + QKV projection. 64 tokens/block, 256 threads.
// LN -> Xs (LDS bf16, never hits HBM), then 3 GEMMs with B-frags read
// directly from global wt (L2-resident). Q/K: [seq][h][tok][d]; V: [seq][h][d][tok].
__global__ void __launch_bounds__(256) k_lnqkv(const float* __restrict__ pe,
        const float* __restrict__ g, const float* __restrict__ bia,
        const u16* __restrict__ wt,
        const float* __restrict__ bq, const float* __restrict__ bk,
        const float* __restrict__ bv,
        u16* __restrict__ Q, u16* __restrict__ Kb, u16* __restrict__ Vt) {
    __shared__ u16 Xs[64 * 136];   // 17.4 KB, row pitch 17 granules
    int tid = threadIdx.x;
    int m0 = blockIdx.x * 64;

    // ---- Phase 1: LayerNorm (4 threads/token) ----
    {
        int tl = tid >> 2;          // local token
        int q = tid & 3;
        const float4* src = reinterpret_cast<const float4*>(pe + (size_t)(m0 + tl) * EMB);
        float4 v[8];
        float s = 0.f, ss = 0.f;
#pragma unroll
        for (int i = 0; i < 8; ++i) {
            v[i] = src[i * 4 + q];
            s += v[i].x + v[i].y + v[i].z + v[i].w;
            ss += v[i].x * v[i].x + v[i].y * v[i].y + v[i].z * v[i].z + v[i].w * v[i].w;
        }
        s += __shfl_xor(s, 1); ss += __shfl_xor(ss, 1);
        s += __shfl_xor(s, 2); ss += __shfl_xor(ss, 2);
        float mean = s * (1.f / EMB);
        float var = ss * (1.f / EMB) - mean * mean;
        float rstd = rsqrtf(var + 1e-5f);
#pragma unroll
        for (int i = 0; i < 8; ++i) {
            int c = i * 16 + q * 4;
            float4 gg = *reinterpret_cast<const float4*>(g + c);
            float4 bb = *reinterpret_cast<const float4*>(bia + c);
            u16 r0 = f2bf((v[i].x - mean) * rstd * gg.x + bb.x);
            u16 r1 = f2bf((v[i].y - mean) * rstd * gg.y + bb.y);
            u16 r2 = f2bf((v[i].z - mean) * rstd * gg.z + bb.z);
            u16 r3 = f2bf((v[i].w - mean) * rstd * gg.w + bb.w);
            uint2 packed;
            packed.x = (u32)r0 | ((u32)r1 << 16);
            packed.y = (u32)r2 | ((u32)r3 << 16);
            *reinterpret_cast<uint2*>(&Xs[tl * 136 + c]) = packed;
        }
    }
    __syncthreads();

    // ---- Phase 2: three GEMMs (Xs read-only; no further barriers) ----
    int lane = tid & 63, wave = tid >> 6;
    int lo = lane & 15, hi = lane >> 4;
    bf16x8 a[4];
#pragma unroll
    for (int kk = 0; kk < 4; ++kk)
        a[kk] = *reinterpret_cast<const bf16x8*>(&Xs[(wave * 16 + lo) * 136 + kk * 32 + hi * 8]);

#pragma unroll
    for (int which = 0; which < 3; ++which) {
        const u16* wbase = wt + which * 16384;
        f32x4 acc[8];
#pragma unroll
        for (int c = 0; c < 8; ++c) acc[c] = f32x4{0.f, 0.f, 0.f, 0.f};
#pragma unroll
        for (int kk = 0; kk < 4; ++kk) {
#pragma unroll
            for (int c = 0; c < 8; ++c) {
                bf16x8 b = *reinterpret_cast<const bf16x8*>(wbase + (c * 16 + lo) * 128 + kk * 32 + hi * 8);
                acc[c] = __builtin_amdgcn_mfma_f32_16x16x32_bf16(a[kk], b, acc[c], 0, 0, 0);
            }
        }
        const float* bias = which == 0 ? bq : which == 1 ? bk : bv;
#pragma unroll
        for (int c = 0; c < 8; ++c) {
            int col = c * 16 + lo;      // h = c, d = lo
            float bval = bias[col];
            if (which < 2) {
                u16* dst = which == 0 ? Q : Kb;
#pragma unroll
                for (int j = 0; j < 4; ++j) {
                    int t = m0 + wave * 16 + hi * 4 + j;
                    float vvv = acc[c][j] + bval;
                    if (which == 0) vvv *= 0.25f;
                    dst[(size_t)(t >> 7) * 16384 + c * 2048 + (t & 127) * 16 + lo] = f2bf(vvv);
                }
            } else {
                int t0 = m0 + wave * 16 + hi * 4;
                uint2 packed;
                packed.x = (u32)f2bf(acc[c][0] + bval) | ((u32)f2bf(acc[c][1] + bval) << 16);
                packed.y = (u32)f2bf(acc[c][2] + bval) | ((u32)f2bf(acc[c][3] + bval) << 16);
                *reinterpret_cast<uint2*>(&Vt[(size_t)(t0 >> 7) * 16384 + c * 2048 + lo * 128 + (t0 & 127)]) = packed;
            }
        }
    }
}

// ---------------------------------------------------------------------------
// Fused attention + output projection. One block per seq row (256 blocks),
// 512 threads = 8 waves, wave = head. Attention per 32-q tile fully in
// registers (round-2-verified math); ctx -> XOR-swizzled LDS; then each wave
// computes a 16-token stripe of ctx @ Wo + bo, * mask -> fp32 out.
__global__ void __launch_bounds__(512) k_attnout(const u16* __restrict__ Q,
        const u16* __restrict__ Kb, const u16* __restrict__ Vt,
        const u16* __restrict__ wt, const float* __restrict__ bo,
        const float* __restrict__ mask, float* __restrict__ out) {
    __shared__ u16 ctxs[128 * 128];   // 32 KB, XOR-swizzled: byte ^= (tok&7)<<4
    int tid = threadIdx.x;
    int lane = tid & 63;
    int h = tid >> 6;                 // wave = head
    int seq = blockIdx.x;
    size_t base = (size_t)seq * 16384 + (size_t)h * 2048;

    int lo = lane & 31, hi = lane >> 5;
    const f32x16 zero = {};

    // K fragments for the whole head (reused across all 4 q-tiles)
    bf16x8 kf[4];
#pragma unroll
    for (int t = 0; t < 4; ++t)
        kf[t] = *reinterpret_cast<const bf16x8*>(Kb + base + (size_t)(t * 32 + lo) * 16 + hi * 8);

    for (int qt = 0; qt < 4; ++qt) {
        bf16x8 qf = *reinterpret_cast<const bf16x8*>(Q + base + (size_t)(qt * 32 + lo) * 16 + hi * 8);
        f32x16 s[4];
#pragma unroll
        for (int t = 0; t < 4; ++t)
            s[t] = __builtin_amdgcn_mfma_f32_32x32x16_bf16(kf[t], qf, zero, 0, 0, 0);

        // softmax over k (lane has 64 of 128 k for q=lo; partner lane^32 has rest)
        float m = s[0][0];
#pragma unroll
        for (int t = 0; t < 4; ++t)
#pragma unroll
            for (int r = 0; r < 16; ++r) m = fmaxf(m, s[t][r]);
        m = fmaxf(m, __shfl_xor(m, 32));
        float sum = 0.f;
#pragma unroll
        for (int t = 0; t < 4; ++t)
#pragma unroll
            for (int r = 0; r < 16; ++r) {
                float p = __expf(s[t][r] - m);
                s[t][r] = p;
                sum += p;
            }
        sum += __shfl_xor(sum, 32);
        float inv = 1.f / sum;

        // PV: O^T = V^T @ P^T, 8 chunks of 16 k
        f32x16 o = {};
#pragma unroll
        for (int c = 0; c < 8; ++c) {
            int t = c >> 1, hf = (c & 1) * 8;
            u32 x0 = cvtpk(s[t][hf + 0], s[t][hf + 1]);
            u32 x1 = cvtpk(s[t][hf + 2], s[t][hf + 3]);
            u32 y0 = cvtpk(s[t][hf + 4], s[t][hf + 5]);
            u32 y1 = cvtpk(s[t][hf + 6], s[t][hf + 7]);
            plswap(x0, y0);
            plswap(x1, y1);
            union { u32 w[4]; bf16x8 v; } pb;
            pb.w[0] = x0; pb.w[1] = x1; pb.w[2] = y0; pb.w[3] = y1;
            bf16x8 va = *reinterpret_cast<const bf16x8*>(Vt + base + (size_t)(lo & 15) * 128 + c * 16 + hi * 8);
            o = __builtin_amdgcn_mfma_f32_32x32x16_bf16(va, pb.v, o, 0, 0, 0);
        }

        // ctx tile -> swizzled LDS: tok=qt*32+lo, cols h*16 + {4hi..4hi+3, 8+4hi..}
        int tok = qt * 32 + lo;
        u32 off0 = (u32)(tok * 256 + h * 32 + 8 * hi) ^ ((tok & 7) << 4);
        u32 off1 = (u32)(tok * 256 + h * 32 + 16 + 8 * hi) ^ ((tok & 7) << 4);
        uint2 p0, p1;
        p0.x = (u32)f2bf(o[0] * inv) | ((u32)f2bf(o[1] * inv) << 16);
        p0.y = (u32)f2bf(o[2] * inv) | ((u32)f2bf(o[3] * inv) << 16);
        p1.x = (u32)f2bf(o[4] * inv) | ((u32)f2bf(o[5] * inv) << 16);
        p1.y = (u32)f2bf(o[6] * inv) | ((u32)f2bf(o[7] * inv) << 16);
        *reinterpret_cast<uint2*>(reinterpret_cast<char*>(ctxs) + off0) = p0;
        *reinterpret_cast<uint2*>(reinterpret_cast<char*>(ctxs) + off1) = p1;
    }
    __syncthreads();

    // ---- Output projection: wave h does tokens [h*16, h*16+16) ----
    int lo4 = lane & 15, hi4 = lane >> 4;
    const u16* wo = wt + 3 * 16384;
    f32x4 acc[8];
#pragma unroll
    for (int c = 0; c < 8; ++c) acc[c] = f32x4{0.f, 0.f, 0.f, 0.f};
#pragma unroll
    for (int kk = 0; kk < 4; ++kk) {
        int tokrow = h * 16 + lo4;
        u32 aoff = (u32)(tokrow * 256 + kk * 64 + hi4 * 16) ^ ((tokrow & 7) << 4);
        bf16x8 a = *reinterpret_cast<const bf16x8*>(reinterpret_cast<char*>(ctxs) + aoff);
#pragma unroll
        for (int c = 0; c < 8; ++c) {
            bf16x8 b = *reinterpret_cast<const bf16x8*>(wo + (c * 16 + lo4) * 128 + kk * 32 + hi4 * 8);
            acc[c] = __builtin_amdgcn_mfma_f32_16x16x32_bf16(a, b, acc[c], 0, 0, 0);
        }
    }
#pragma unroll
    for (int c = 0; c < 8; ++c) {
        int col = c * 16 + lo4;
        float bval = bo[col];
#pragma unroll
        for (int j = 0; j < 4; ++j) {
            int t = seq * 128 + h * 16 + hi4 * 4 + j;
            out[(size_t)t * EMB + col] = (acc[c][j] + bval) * mask[t];
        }
    }
}

// ---------------------------------------------------------------------------
extern "C" void kernel_launch(void* const* d_in, const int* in_sizes, int n_in,
                              void* d_out, int out_size, void* d_ws, size_t ws_size,
                              hipStream_t stream) {
    const float* pe   = (const float*)d_in[0];
    const float* mask = (const float*)d_in[1];
    const float* ln_g = (const float*)d_in[2];
    const float* ln_b = (const float*)d_in[3];
    const float* wq   = (const float*)d_in[4];
    const float* bq   = (const float*)d_in[5];
    const float* wk   = (const float*)d_in[6];
    const float* bk   = (const float*)d_in[7];
    const float* wv   = (const float*)d_in[8];
    const float* bv   = (const float*)d_in[9];
    const float* wo   = (const float*)d_in[10];
    const float* bo   = (const float*)d_in[11];
    float* out = (float*)d_out;

    u16* W   = (u16*)d_ws;
    u16* Q   = W + 4194304;          // [seq][h][tok][d]
    u16* Kb  = W + 8388608;
    u16* Vt  = W + 12582912;         // [seq][h][d][tok]
    u16* wt  = W + 20971520;         // 4 x [n][k] bf16

    hipLaunchKernelGGL(k_prep,    dim3(256), dim3(256), 0, stream, wq, wk, wv, wo, wt);
    hipLaunchKernelGGL(k_lnqkv,   dim3(512), dim3(256), 0, stream, pe, ln_g, ln_b, wt, bq, bk, bv, Q, Kb, Vt);
    hipLaunchKernelGGL(k_attnout, dim3(256), dim3(512), 0, stream, Q, Kb, Vt, wt, bo, mask, out);
}

// Round 4
// 44.760 us; speedup vs baseline: 1.4412x; 1.4412x over previous
//
#include <hip/hip_runtime.h>
#include <hip/hip_bf16.h>

typedef __attribute__((ext_vector_type(8))) short bf16x8;
typedef __attribute__((ext_vector_type(4))) float f32x4;
typedef __attribute__((ext_vector_type(16))) float f32x16;
typedef __attribute__((ext_vector_type(2))) unsigned int u32x2;
typedef unsigned short u16;
typedef unsigned int u32;

#define EMB 128
#define HEADS 8
#define HD 16
#define NB 2
#define NN 128
#define SEQ (NB*NN)
#define NTOK (SEQ*NN)

// round-to-nearest-even fp32 -> bf16
static __device__ __forceinline__ u16 f2bf(float f) {
    union { float f; u32 u; } v; v.f = f;
    u32 u = v.u;
    return (u16)((u + 0x7FFFu + ((u >> 16) & 1u)) >> 16);
}

static __device__ __forceinline__ u32 cvtpk(float a, float b) {
    u32 r;
    asm("v_cvt_pk_bf16_f32 %0, %1, %2" : "=v"(r) : "v"(a), "v"(b));
    return r;
}

// exchange: a' = [a.lo32 | b.lo32(partner)], b' = [a.hi32(partner) | b.hi32]
static __device__ __forceinline__ void plswap(u32& a, u32& b) {
#if __has_builtin(__builtin_amdgcn_permlane32_swap)
    u32x2 r = __builtin_amdgcn_permlane32_swap(a, b, false, false);
    a = r[0]; b = r[1];
#else
    u32 sa = __shfl_xor(a, 32), sb = __shfl_xor(b, 32);
    bool hi = (threadIdx.x & 32) != 0;
    u32 na = hi ? sb : a;
    u32 nb = hi ? b : sa;
    a = na; b = nb;
#endif
}

// ---------------------------------------------------------------------------
// Weight prep: wt[mat][n][k] = bf16(w[mat][k][n]), mat: q,k,v,o
__global__ void __launch_bounds__(256) k_prep(const float* __restrict__ wq,
        const float* __restrict__ wk, const float* __restrict__ wv,
        const float* __restrict__ wo, u16* __restrict__ wt) {
    int i = blockIdx.x * 256 + threadIdx.x;
    int mat = i >> 14, rem = i & 16383;
    int k = rem >> 7, n = rem & 127;
    const float* src = mat == 0 ? wq : mat == 1 ? wk : mat == 2 ? wv : wo;
    wt[mat * 16384 + n * 128 + k] = f2bf(src[rem]);
}

// ---------------------------------------------------------------------------
// Fused LayerNorm + QKV projection. One block per seq row: 512 threads =
// 8 waves = 8 heads. LN -> Xs (LDS, 128 tok x 128, pitch 136). Wave h keeps
// its head's W_q/k/v column-slices as register-resident B-frags (48 VGPRs,
// loaded once) and sweeps 8 token-subtiles x 3 mats x 4 K-chunks of MFMA.
// Q/K: [seq][h][tok][d]; V: [seq][h][d][tok]  (same layouts as before).
__global__ void __launch_bounds__(512) k_lnqkv(const float* __restrict__ pe,
        const float* __restrict__ g, const float* __restrict__ bia,
        const u16* __restrict__ wt,
        const float* __restrict__ bq, const float* __restrict__ bk,
        const float* __restrict__ bv,
        u16* __restrict__ Q, u16* __restrict__ Kb, u16* __restrict__ Vt) {
    __shared__ u16 Xs[128 * 136];   // 34 KB
    int tid = threadIdx.x;
    int seq = blockIdx.x;
    size_t t0 = (size_t)seq * 128;

    // ---- Phase 1: LayerNorm, 4 threads/token, 128 tokens ----
    {
        int tl = tid >> 2;
        int q = tid & 3;
        const float4* src = reinterpret_cast<const float4*>(pe + (t0 + tl) * EMB);
        float4 v[8];
        float s = 0.f, ss = 0.f;
#pragma unroll
        for (int i = 0; i < 8; ++i) {
            v[i] = src[i * 4 + q];
            s += v[i].x + v[i].y + v[i].z + v[i].w;
            ss += v[i].x * v[i].x + v[i].y * v[i].y + v[i].z * v[i].z + v[i].w * v[i].w;
        }
        s += __shfl_xor(s, 1); ss += __shfl_xor(ss, 1);
        s += __shfl_xor(s, 2); ss += __shfl_xor(ss, 2);
        float mean = s * (1.f / EMB);
        float var = ss * (1.f / EMB) - mean * mean;
        float rstd = rsqrtf(var + 1e-5f);
#pragma unroll
        for (int i = 0; i < 8; ++i) {
            int c = i * 16 + q * 4;
            float4 gg = *reinterpret_cast<const float4*>(g + c);
            float4 bb = *reinterpret_cast<const float4*>(bia + c);
            uint2 packed;
            packed.x = (u32)f2bf((v[i].x - mean) * rstd * gg.x + bb.x)
                     | ((u32)f2bf((v[i].y - mean) * rstd * gg.y + bb.y) << 16);
            packed.y = (u32)f2bf((v[i].z - mean) * rstd * gg.z + bb.z)
                     | ((u32)f2bf((v[i].w - mean) * rstd * gg.w + bb.w) << 16);
            *reinterpret_cast<uint2*>(&Xs[tl * 136 + c]) = packed;
        }
    }
    __syncthreads();

    // ---- Phase 2: per-head QKV GEMM, W register-resident ----
    int lane = tid & 63, h = tid >> 6;
    int lo = lane & 15, hi = lane >> 4;

    bf16x8 bf[3][4];
#pragma unroll
    for (int mat = 0; mat < 3; ++mat)
#pragma unroll
        for (int kk = 0; kk < 4; ++kk)
            bf[mat][kk] = *reinterpret_cast<const bf16x8*>(
                wt + mat * 16384 + (h * 16 + lo) * 128 + kk * 32 + hi * 8);

    float bq_ = bq[h * 16 + lo];
    float bk_ = bk[h * 16 + lo];
    float bv_ = bv[h * 16 + lo];
    size_t base = (size_t)seq * 16384 + (size_t)h * 2048;

#pragma unroll
    for (int sub = 0; sub < 8; ++sub) {
        bf16x8 a[4];
#pragma unroll
        for (int kk = 0; kk < 4; ++kk)
            a[kk] = *reinterpret_cast<const bf16x8*>(&Xs[(sub * 16 + lo) * 136 + kk * 32 + hi * 8]);
        f32x4 aq = {}, ak = {}, av = {};
#pragma unroll
        for (int kk = 0; kk < 4; ++kk) {
            aq = __builtin_amdgcn_mfma_f32_16x16x32_bf16(a[kk], bf[0][kk], aq, 0, 0, 0);
            ak = __builtin_amdgcn_mfma_f32_16x16x32_bf16(a[kk], bf[1][kk], ak, 0, 0, 0);
            av = __builtin_amdgcn_mfma_f32_16x16x32_bf16(a[kk], bf[2][kk], av, 0, 0, 0);
        }
        // D: col(=d within head) = lo, row(=token) = sub*16 + hi*4 + j
#pragma unroll
        for (int j = 0; j < 4; ++j) {
            int tok = sub * 16 + hi * 4 + j;
            Q[base + tok * 16 + lo]  = f2bf((aq[j] + bq_) * 0.25f);
            Kb[base + tok * 16 + lo] = f2bf(ak[j] + bk_);
        }
        int tokv = sub * 16 + hi * 4;
        uint2 pv;
        pv.x = (u32)f2bf(av[0] + bv_) | ((u32)f2bf(av[1] + bv_) << 16);
        pv.y = (u32)f2bf(av[2] + bv_) | ((u32)f2bf(av[3] + bv_) << 16);
        *reinterpret_cast<uint2*>(&Vt[base + (size_t)lo * 128 + tokv]) = pv;
    }
}

// ---------------------------------------------------------------------------
// Fused attention + output projection. One block per seq row (256 blocks),
// 512 threads = 8 waves, wave = head. Attention per 32-q tile fully in
// registers; ctx -> XOR-swizzled LDS; then each wave computes a 16-token
// stripe of ctx @ Wo + bo, * mask -> fp32 out.
__global__ void __launch_bounds__(512) k_attnout(const u16* __restrict__ Q,
        const u16* __restrict__ Kb, const u16* __restrict__ Vt,
        const u16* __restrict__ wt, const float* __restrict__ bo,
        const float* __restrict__ mask, float* __restrict__ out) {
    __shared__ u16 ctxs[128 * 128];   // 32 KB, XOR-swizzled: byte ^= (tok&7)<<4
    int tid = threadIdx.x;
    int lane = tid & 63;
    int h = tid >> 6;
    int seq = blockIdx.x;
    size_t base = (size_t)seq * 16384 + (size_t)h * 2048;

    int lo = lane & 31, hi = lane >> 5;
    const f32x16 zero = {};

    bf16x8 kf[4];
#pragma unroll
    for (int t = 0; t < 4; ++t)
        kf[t] = *reinterpret_cast<const bf16x8*>(Kb + base + (size_t)(t * 32 + lo) * 16 + hi * 8);

    for (int qt = 0; qt < 4; ++qt) {
        bf16x8 qf = *reinterpret_cast<const bf16x8*>(Q + base + (size_t)(qt * 32 + lo) * 16 + hi * 8);
        f32x16 s[4];
#pragma unroll
        for (int t = 0; t < 4; ++t)
            s[t] = __builtin_amdgcn_mfma_f32_32x32x16_bf16(kf[t], qf, zero, 0, 0, 0);

        float m = s[0][0];
#pragma unroll
        for (int t = 0; t < 4; ++t)
#pragma unroll
            for (int r = 0; r < 16; ++r) m = fmaxf(m, s[t][r]);
        m = fmaxf(m, __shfl_xor(m, 32));
        float sum = 0.f;
#pragma unroll
        for (int t = 0; t < 4; ++t)
#pragma unroll
            for (int r = 0; r < 16; ++r) {
                float p = __expf(s[t][r] - m);
                s[t][r] = p;
                sum += p;
            }
        sum += __shfl_xor(sum, 32);
        float inv = 1.f / sum;

        f32x16 o = {};
#pragma unroll
        for (int c = 0; c < 8; ++c) {
            int t = c >> 1, hf = (c & 1) * 8;
            u32 x0 = cvtpk(s[t][hf + 0], s[t][hf + 1]);
            u32 x1 = cvtpk(s[t][hf + 2], s[t][hf + 3]);
            u32 y0 = cvtpk(s[t][hf + 4], s[t][hf + 5]);
            u32 y1 = cvtpk(s[t][hf + 6], s[t][hf + 7]);
            plswap(x0, y0);
            plswap(x1, y1);
            union { u32 w[4]; bf16x8 v; } pb;
            pb.w[0] = x0; pb.w[1] = x1; pb.w[2] = y0; pb.w[3] = y1;
            bf16x8 va = *reinterpret_cast<const bf16x8*>(Vt + base + (size_t)(lo & 15) * 128 + c * 16 + hi * 8);
            o = __builtin_amdgcn_mfma_f32_32x32x16_bf16(va, pb.v, o, 0, 0, 0);
        }

        int tok = qt * 32 + lo;
        u32 off0 = (u32)(tok * 256 + h * 32 + 8 * hi) ^ ((tok & 7) << 4);
        u32 off1 = (u32)(tok * 256 + h * 32 + 16 + 8 * hi) ^ ((tok & 7) << 4);
        uint2 p0, p1;
        p0.x = (u32)f2bf(o[0] * inv) | ((u32)f2bf(o[1] * inv) << 16);
        p0.y = (u32)f2bf(o[2] * inv) | ((u32)f2bf(o[3] * inv) << 16);
        p1.x = (u32)f2bf(o[4] * inv) | ((u32)f2bf(o[5] * inv) << 16);
        p1.y = (u32)f2bf(o[6] * inv) | ((u32)f2bf(o[7] * inv) << 16);
        *reinterpret_cast<uint2*>(reinterpret_cast<char*>(ctxs) + off0) = p0;
        *reinterpret_cast<uint2*>(reinterpret_cast<char*>(ctxs) + off1) = p1;
    }
    __syncthreads();

    // ---- Output projection: wave h does tokens [h*16, h*16+16) ----
    int lo4 = lane & 15, hi4 = lane >> 4;
    const u16* wo = wt + 3 * 16384;
    f32x4 acc[8];
#pragma unroll
    for (int c = 0; c < 8; ++c) acc[c] = f32x4{0.f, 0.f, 0.f, 0.f};
#pragma unroll
    for (int kk = 0; kk < 4; ++kk) {
        int tokrow = h * 16 + lo4;
        u32 aoff = (u32)(tokrow * 256 + kk * 64 + hi4 * 16) ^ ((tokrow & 7) << 4);
        bf16x8 a = *reinterpret_cast<const bf16x8*>(reinterpret_cast<char*>(ctxs) + aoff);
#pragma unroll
        for (int c = 0; c < 8; ++c) {
            bf16x8 b = *reinterpret_cast<const bf16x8*>(wo + (c * 16 + lo4) * 128 + kk * 32 + hi4 * 8);
            acc[c] = __builtin_amdgcn_mfma_f32_16x16x32_bf16(a, b, acc[c], 0, 0, 0);
        }
    }
#pragma unroll
    for (int c = 0; c < 8; ++c) {
        int col = c * 16 + lo4;
        float bval = bo[col];
#pragma unroll
        for (int j = 0; j < 4; ++j) {
            int t = seq * 128 + h * 16 + hi4 * 4 + j;
            out[(size_t)t * EMB + col] = (acc[c][j] + bval) * mask[t];
        }
    }
}

// ---------------------------------------------------------------------------
extern "C" void kernel_launch(void* const* d_in, const int* in_sizes, int n_in,
                              void* d_out, int out_size, void* d_ws, size_t ws_size,
                              hipStream_t stream) {
    const float* pe   = (const float*)d_in[0];
    const float* mask = (const float*)d_in[1];
    const float* ln_g = (const float*)d_in[2];
    const float* ln_b = (const float*)d_in[3];
    const float* wq   = (const float*)d_in[4];
    const float* bq   = (const float*)d_in[5];
    const float* wk   = (const float*)d_in[6];
    const float* bk   = (const float*)d_in[7];
    const float* wv   = (const float*)d_in[8];
    const float* bv   = (const float*)d_in[9];
    const float* wo   = (const float*)d_in[10];
    const float* bo   = (const float*)d_in[11];
    float* out = (float*)d_out;

    u16* W   = (u16*)d_ws;
    u16* Q   = W + 4194304;          // [seq][h][tok][d]
    u16* Kb  = W + 8388608;
    u16* Vt  = W + 12582912;         // [seq][h][d][tok]
    u16* wt  = W + 20971520;         // 4 x [n][k] bf16

    hipLaunchKernelGGL(k_prep,    dim3(256), dim3(256), 0, stream, wq, wk, wv, wo, wt);
    hipLaunchKernelGGL(k_lnqkv,   dim3(256), dim3(512), 0, stream, pe, ln_g, ln_b, wt, bq, bk, bv, Q, Kb, Vt);
    hipLaunchKernelGGL(k_attnout, dim3(256), dim3(512), 0, stream, Q, Kb, Vt, wt, bo, mask, out);
}

// Round 5
// 36.670 us; speedup vs baseline: 1.7592x; 1.2206x over previous
//
#include <hip/hip_runtime.h>
#include <hip/hip_bf16.h>

typedef __attribute__((ext_vector_type(8))) short bf16x8;
typedef __attribute__((ext_vector_type(4))) float f32x4;
typedef __attribute__((ext_vector_type(16))) float f32x16;
typedef __attribute__((ext_vector_type(2))) unsigned int u32x2;
typedef unsigned short u16;
typedef unsigned int u32;

#define EMB 128
#define HEADS 8
#define HD 16
#define NB 2
#define NN 128
#define SEQ (NB*NN)
#define NTOK (SEQ*NN)

// round-to-nearest-even fp32 -> bf16
static __device__ __forceinline__ u16 f2bf(float f) {
    union { float f; u32 u; } v; v.f = f;
    u32 u = v.u;
    return (u16)((u + 0x7FFFu + ((u >> 16) & 1u)) >> 16);
}

static __device__ __forceinline__ u32 cvtpk(float a, float b) {
    u32 r;
    asm("v_cvt_pk_bf16_f32 %0, %1, %2" : "=v"(r) : "v"(a), "v"(b));
    return r;
}

// exchange: a' = [a.lo32 | b.lo32(partner)], b' = [a.hi32(partner) | b.hi32]
static __device__ __forceinline__ void plswap(u32& a, u32& b) {
#if __has_builtin(__builtin_amdgcn_permlane32_swap)
    u32x2 r = __builtin_amdgcn_permlane32_swap(a, b, false, false);
    a = r[0]; b = r[1];
#else
    u32 sa = __shfl_xor(a, 32), sb = __shfl_xor(b, 32);
    bool hi = (threadIdx.x & 32) != 0;
    u32 na = hi ? sb : a;
    u32 nb = hi ? b : sa;
    a = na; b = nb;
#endif
}

// ---------------------------------------------------------------------------
// Weight prep: wt[mat][n][k] = bf16(w[mat][k][n]), mat: q,k,v,o
__global__ void __launch_bounds__(256) k_prep(const float* __restrict__ wq,
        const float* __restrict__ wk, const float* __restrict__ wv,
        const float* __restrict__ wo, u16* __restrict__ wt) {
    int i = blockIdx.x * 256 + threadIdx.x;
    int mat = i >> 14, rem = i & 16383;
    int k = rem >> 7, n = rem & 127;
    const float* src = mat == 0 ? wq : mat == 1 ? wk : mat == 2 ? wv : wo;
    wt[mat * 16384 + n * 128 + k] = f2bf(src[rem]);
}

// ---------------------------------------------------------------------------
// Fully fused: LN -> QKV (LDS) -> attention -> out-proj. One block per seq
// row (256 blocks = 256 CUs), 512 threads = 8 waves = 8 heads.
// LDS map (132 KB):
//   [0,      34816)  Xs   : LN'd X, [128 tok][136 u16]  (reused as ctxs)
//   [34816,  67584)  Qs   : [8 h][128 tok][16 d] u16, XOR-swz bit4
//   [67584, 100352)  Ks   : same as Qs
//   [100352,135168)  Vs   : [8 h][16 d][136 tok-pitch] u16
__global__ void __launch_bounds__(512) k_fused(const float* __restrict__ pe,
        const float* __restrict__ g, const float* __restrict__ bia,
        const u16* __restrict__ wt,
        const float* __restrict__ bq, const float* __restrict__ bk,
        const float* __restrict__ bv, const float* __restrict__ bo,
        const float* __restrict__ mask, float* __restrict__ out) {
    __shared__ __align__(16) char smem[135168];
    u16* Xs = reinterpret_cast<u16*>(smem);            // pitch 136
    u16* Qs = reinterpret_cast<u16*>(smem + 34816);
    u16* Ks = reinterpret_cast<u16*>(smem + 67584);
    u16* Vs = reinterpret_cast<u16*>(smem + 100352);
    char* ctxs = smem;                                  // 256B-pitch, swizzled

    int tid = threadIdx.x;
    int seq = blockIdx.x;
    int lane = tid & 63, h = tid >> 6;
    int lo = lane & 15, hi = lane >> 4;

    // W fragments for this head (registers; issued early, L2-resident)
    bf16x8 bf[3][4];
#pragma unroll
    for (int mat = 0; mat < 3; ++mat)
#pragma unroll
        for (int kk = 0; kk < 4; ++kk)
            bf[mat][kk] = *reinterpret_cast<const bf16x8*>(
                wt + mat * 16384 + (h * 16 + lo) * 128 + kk * 32 + hi * 8);
    float bq_ = bq[h * 16 + lo];
    float bk_ = bk[h * 16 + lo];
    float bv_ = bv[h * 16 + lo];

    // ---- Phase 1: LayerNorm, 4 threads/token, 128 tokens ----
    {
        int tl = tid >> 2;
        int q = tid & 3;
        const float4* src = reinterpret_cast<const float4*>(pe + (size_t)(seq * 128 + tl) * EMB);
        float4 v[8];
        float s = 0.f, ss = 0.f;
#pragma unroll
        for (int i = 0; i < 8; ++i) {
            v[i] = src[i * 4 + q];
            s += v[i].x + v[i].y + v[i].z + v[i].w;
            ss += v[i].x * v[i].x + v[i].y * v[i].y + v[i].z * v[i].z + v[i].w * v[i].w;
        }
        s += __shfl_xor(s, 1); ss += __shfl_xor(ss, 1);
        s += __shfl_xor(s, 2); ss += __shfl_xor(ss, 2);
        float mean = s * (1.f / EMB);
        float var = ss * (1.f / EMB) - mean * mean;
        float rstd = rsqrtf(var + 1e-5f);
#pragma unroll
        for (int i = 0; i < 8; ++i) {
            int c = i * 16 + q * 4;
            float4 gg = *reinterpret_cast<const float4*>(g + c);
            float4 bb = *reinterpret_cast<const float4*>(bia + c);
            uint2 packed;
            packed.x = (u32)f2bf((v[i].x - mean) * rstd * gg.x + bb.x)
                     | ((u32)f2bf((v[i].y - mean) * rstd * gg.y + bb.y) << 16);
            packed.y = (u32)f2bf((v[i].z - mean) * rstd * gg.z + bb.z)
                     | ((u32)f2bf((v[i].w - mean) * rstd * gg.w + bb.w) << 16);
            *reinterpret_cast<uint2*>(&Xs[tl * 136 + c]) = packed;
        }
    }
    __syncthreads();

    // ---- Phase 2: per-head QKV GEMM (W in regs), results -> LDS ----
#pragma unroll
    for (int sub = 0; sub < 8; ++sub) {
        bf16x8 a[4];
#pragma unroll
        for (int kk = 0; kk < 4; ++kk)
            a[kk] = *reinterpret_cast<const bf16x8*>(&Xs[(sub * 16 + lo) * 136 + kk * 32 + hi * 8]);
        f32x4 aq = {}, ak = {}, av = {};
#pragma unroll
        for (int kk = 0; kk < 4; ++kk) {
            aq = __builtin_amdgcn_mfma_f32_16x16x32_bf16(a[kk], bf[0][kk], aq, 0, 0, 0);
            ak = __builtin_amdgcn_mfma_f32_16x16x32_bf16(a[kk], bf[1][kk], ak, 0, 0, 0);
            av = __builtin_amdgcn_mfma_f32_16x16x32_bf16(a[kk], bf[2][kk], av, 0, 0, 0);
        }
        // D: col(=d) = lo, row(=token) = sub*16 + hi*4 + j
#pragma unroll
        for (int j = 0; j < 4; ++j) {
            int tok = sub * 16 + hi * 4 + j;
            int idx = (h << 11) + ((tok * 16 + lo) ^ ((tok & 4) << 1));
            Qs[idx] = f2bf((aq[j] + bq_) * 0.25f);
            Ks[idx] = f2bf(ak[j] + bk_);
        }
        int tokv = sub * 16 + hi * 4;
        uint2 pv;
        pv.x = (u32)f2bf(av[0] + bv_) | ((u32)f2bf(av[1] + bv_) << 16);
        pv.y = (u32)f2bf(av[2] + bv_) | ((u32)f2bf(av[3] + bv_) << 16);
        *reinterpret_cast<uint2*>(&Vs[h * 2176 + lo * 136 + tokv]) = pv;
    }
    __syncthreads();

    // ---- Phase 3: attention (reads Qs/Ks/Vs; writes ctxs = Xs region) ----
    {
        int lo2 = lane & 31, hi2 = lane >> 5;
        int swz = (lo2 & 4) << 1;            // tok&4 == lo2&4 for tok = t*32+lo2
        const f32x16 zero = {};

        bf16x8 kf[4];
#pragma unroll
        for (int t = 0; t < 4; ++t)
            kf[t] = *reinterpret_cast<const bf16x8*>(
                &Ks[(h << 11) + (((t * 32 + lo2) * 16 + hi2 * 8) ^ swz)]);

        for (int qt = 0; qt < 4; ++qt) {
            bf16x8 qf = *reinterpret_cast<const bf16x8*>(
                &Qs[(h << 11) + (((qt * 32 + lo2) * 16 + hi2 * 8) ^ swz)]);
            f32x16 s[4];
#pragma unroll
            for (int t = 0; t < 4; ++t)
                s[t] = __builtin_amdgcn_mfma_f32_32x32x16_bf16(kf[t], qf, zero, 0, 0, 0);

            float m = s[0][0];
#pragma unroll
            for (int t = 0; t < 4; ++t)
#pragma unroll
                for (int r = 0; r < 16; ++r) m = fmaxf(m, s[t][r]);
            m = fmaxf(m, __shfl_xor(m, 32));
            float sum = 0.f;
#pragma unroll
            for (int t = 0; t < 4; ++t)
#pragma unroll
                for (int r = 0; r < 16; ++r) {
                    float p = __expf(s[t][r] - m);
                    s[t][r] = p;
                    sum += p;
                }
            sum += __shfl_xor(sum, 32);
            float inv = 1.f / sum;

            f32x16 o = {};
#pragma unroll
            for (int c = 0; c < 8; ++c) {
                int t = c >> 1, hf = (c & 1) * 8;
                u32 x0 = cvtpk(s[t][hf + 0], s[t][hf + 1]);
                u32 x1 = cvtpk(s[t][hf + 2], s[t][hf + 3]);
                u32 y0 = cvtpk(s[t][hf + 4], s[t][hf + 5]);
                u32 y1 = cvtpk(s[t][hf + 6], s[t][hf + 7]);
                plswap(x0, y0);
                plswap(x1, y1);
                union { u32 w[4]; bf16x8 v; } pb;
                pb.w[0] = x0; pb.w[1] = x1; pb.w[2] = y0; pb.w[3] = y1;
                bf16x8 va = *reinterpret_cast<const bf16x8*>(
                    &Vs[h * 2176 + (lo2 & 15) * 136 + c * 16 + hi2 * 8]);
                o = __builtin_amdgcn_mfma_f32_32x32x16_bf16(va, pb.v, o, 0, 0, 0);
            }

            int tok = qt * 32 + lo2;
            u32 off0 = (u32)(tok * 256 + h * 32 + 8 * hi2) ^ ((tok & 7) << 4);
            u32 off1 = (u32)(tok * 256 + h * 32 + 16 + 8 * hi2) ^ ((tok & 7) << 4);
            uint2 p0, p1;
            p0.x = (u32)f2bf(o[0] * inv) | ((u32)f2bf(o[1] * inv) << 16);
            p0.y = (u32)f2bf(o[2] * inv) | ((u32)f2bf(o[3] * inv) << 16);
            p1.x = (u32)f2bf(o[4] * inv) | ((u32)f2bf(o[5] * inv) << 16);
            p1.y = (u32)f2bf(o[6] * inv) | ((u32)f2bf(o[7] * inv) << 16);
            *reinterpret_cast<uint2*>(ctxs + off0) = p0;
            *reinterpret_cast<uint2*>(ctxs + off1) = p1;
        }
    }
    __syncthreads();

    // ---- Phase 4: output projection; wave h does tokens [h*16, h*16+16) ----
    {
        const u16* wo = wt + 3 * 16384;
        f32x4 acc[8];
#pragma unroll
        for (int c = 0; c < 8; ++c) acc[c] = f32x4{0.f, 0.f, 0.f, 0.f};
#pragma unroll
        for (int kk = 0; kk < 4; ++kk) {
            int tokrow = h * 16 + lo;
            u32 aoff = (u32)(tokrow * 256 + kk * 64 + hi * 16) ^ ((tokrow & 7) << 4);
            bf16x8 a = *reinterpret_cast<const bf16x8*>(ctxs + aoff);
#pragma unroll
            for (int c = 0; c < 8; ++c) {
                bf16x8 b = *reinterpret_cast<const bf16x8*>(wo + (c * 16 + lo) * 128 + kk * 32 + hi * 8);
                acc[c] = __builtin_amdgcn_mfma_f32_16x16x32_bf16(a, b, acc[c], 0, 0, 0);
            }
        }
#pragma unroll
        for (int c = 0; c < 8; ++c) {
            int col = c * 16 + lo;
            float bval = bo[col];
#pragma unroll
            for (int j = 0; j < 4; ++j) {
                int t = seq * 128 + h * 16 + hi * 4 + j;
                out[(size_t)t * EMB + col] = (acc[c][j] + bval) * mask[t];
            }
        }
    }
}

// ---------------------------------------------------------------------------
extern "C" void kernel_launch(void* const* d_in, const int* in_sizes, int n_in,
                              void* d_out, int out_size, void* d_ws, size_t ws_size,
                              hipStream_t stream) {
    const float* pe   = (const float*)d_in[0];
    const float* mask = (const float*)d_in[1];
    const float* ln_g = (const float*)d_in[2];
    const float* ln_b = (const float*)d_in[3];
    const float* wq   = (const float*)d_in[4];
    const float* bq   = (const float*)d_in[5];
    const float* wk   = (const float*)d_in[6];
    const float* bk   = (const float*)d_in[7];
    const float* wv   = (const float*)d_in[8];
    const float* bv   = (const float*)d_in[9];
    const float* wo   = (const float*)d_in[10];
    const float* bo   = (const float*)d_in[11];
    float* out = (float*)d_out;

    u16* wt = (u16*)d_ws;            // 4 x [n][k] bf16 = 128 KB

    hipLaunchKernelGGL(k_prep,  dim3(256), dim3(256), 0, stream, wq, wk, wv, wo, wt);
    hipLaunchKernelGGL(k_fused, dim3(256), dim3(512), 0, stream, pe, ln_g, ln_b, wt,
                       bq, bk, bv, bo, mask, out);
}